// Round 8
// baseline (219.755 us; speedup 1.0000x reference)
//
#include <hip/hip_runtime.h>
#include <math.h>

// Non-explicit FP stays separate mul/add; explicit fma models the reference's
// contraction (XLA CPU AllowFPOpFusion::Fast). NUMERICS FROZEN SINCE R3:
// absmax 1.117587e-08. Bit-exactness notes:
//  - v_pk_{fma,add,mul,sub}_f32 round each 32-bit lane exactly like scalar.
//  - fused augmented elimination == getrf+laswp+trsm bitwise.
//  - in-place progressive swap: jp triggers at most once; rows move wholesale
//    (cndmask copies bits). Restricting Q-swap/updates to pairs c >= k>>1
//    touches all live columns j>=k (k even: from col k; k odd: from col k-1,
//    dead-L, harmless); excluded lanes hold dead L finalized at step j<k and
//    are never read again (P-axpy consumed lik within its step; strsm reads
//    only rows<=k of column k, which later steps never touch).
//  - pk Q trailing update: live lanes (j>k) get the identical
//    fmaf(-lik,Q[k][j],Q[i][j]); lik read into reg before its lane may be
//    overwritten; dead lanes get unread garbage. [HW-validated R9/R10/R11]
//  - gram upper+x2 weighting: gram is bitwise symmetric (same products, same
//    k-order); only the final f32 sum order changes — established invisible
//    (absmax bit-stable across R4/R6/R7/R9/R10/R11 reorders).
//
// SESSION LEDGER (falsified on HW — do not retry):
//  - PRE-PEAK restructures (sym A2/A4 mirrors, packed ap/a4p, folded U->P/Q):
//    bit-exact but free allocator lands 132-136 VGPR -> above the 128
//    occupancy cliff (4->3 waves/SIMD, dur x1.37). Net loss ~35us.
//  - amdgpu_waves_per_eu(5): 48 VGPR, 1.2GB spill, 541us.
//  - __launch_bounds__(256,2) cap on restructured shape: spills 84MB, 121us.
//  - Occupancy prize (8 waves/SIMD) needs <=64 VGPR: impossible per-thread
//    (data peak ~192+ floats). Cooperative multi-lane split is the only
//    remaining route — high risk, untried.
// THIS BUILD: verbatim R0 pre-peak phases (A..U..P/Q — the register-peak
// region untouched) + POST-PEAK-only instruction cuts (~225 inst, ~4%).
// Tripwire: VGPR>128 => post-peak edits also perturb allocation => revert.
#pragma clang fp contract(off)

typedef float f2 __attribute__((ext_vector_type(2)));

static __device__ __forceinline__ f2 sp(float x) { f2 r; r.x = x; r.y = x; return r; }
static __device__ __forceinline__ f2 sel2(bool d, f2 a, f2 b) {
  f2 r; r.x = d ? a.x : b.x; r.y = d ? a.y : b.y; return r;
}
#define FMA2(A, B, C) __builtin_elementwise_fma((A), (B), (C))

// element access into row-major f2-packed 8x8: m[i*4 + (j>>1)] lane (j&1)
#define EL(m, i, j) (m[(i)*4 + ((j) >> 1)][(j) & 1])

// Full 8x8 matmul, fmaf k-chain, f2-paired over j. Bitwise == R5's scalar mm8
// (full 8-term chains; first term is a mul). Used by the rare squaring path.
__device__ __forceinline__ void mm8p(const f2* __restrict__ A,
                                     const f2* __restrict__ B,
                                     f2* __restrict__ C) {
  #pragma unroll
  for (int i = 0; i < 8; ++i) {
    #pragma unroll
    for (int c = 0; c < 4; ++c) {
      f2 s = sp(EL(A, i, 0)) * B[0*4 + c];
      #pragma unroll
      for (int k = 1; k < 8; ++k)
        s = FMA2(sp(EL(A, i, k)), B[k*4 + c], s);
      C[i*4 + c] = s;
    }
  }
}

// One thread per 8x8 block, 256-thread workgroups, NO min-waves bound:
// (256,1) leaves the allocator free; this shape measures 128 VGPR, zero
// spill, 4 waves/SIMD (peak live = aa+W+V+P = 256 floats).
__global__ __launch_bounds__(256, 1)
void triality_kernel(const float* __restrict__ in, double* __restrict__ acc)
{
  const int t = blockIdx.x * 256 + threadIdx.x;
  const float4* src = (const float4*)(in + (size_t)t * 64);

  float p[64];
  #pragma unroll
  for (int i = 0; i < 16; ++i) {
    float4 q4 = src[i];
    p[4*i+0] = q4.x; p[4*i+1] = q4.y; p[4*i+2] = q4.z; p[4*i+3] = q4.w;
  }

  // A = 0.5*(P - P^T), all 64 entries each with its own sub+mul (R5 exact;
  // diag = +0 exactly).
  f2 aa[32];
  #pragma unroll
  for (int i = 0; i < 8; ++i)
    #pragma unroll
    for (int j = 0; j < 8; ++j)
      EL(aa, i, j) = 0.5f * (p[i*8+j] - p[j*8+i]);

  // 1-norm: per column j, cs = sum_i |a[i][j]| in ascending i (incl. diag +0),
  // then running max — identical op order to R5.
  float l1 = 0.0f;
  #pragma unroll
  for (int j = 0; j < 8; ++j) {
    float cs = 0.0f;
    #pragma unroll
    for (int i = 0; i < 8; ++i) cs = cs + fabsf(EL(aa, i, j));
    l1 = fmaxf(l1, cs);
  }

  // n_squarings = max(0, floor(log2(A_L1 / 3.925724783138660)))
  float fl = floorf(log2f(l1 / 3.925724783138660f));
  int ns = (fl > 0.0f) ? (int)fl : 0;
  if (ns > 0) {
    f2 sc = sp(exp2f((float)(-ns)));   // exact power of two
    #pragma unroll
    for (int e = 0; e < 32; ++e) aa[e] = aa[e] * sc;   // pk_mul, per-lane exact
  }

  // A2 = A*A  (full 8-term fmaf chains, j-paired)
  f2 a2[32];
  #pragma unroll
  for (int i = 0; i < 8; ++i)
    #pragma unroll
    for (int c = 0; c < 4; ++c) {
      f2 s = sp(EL(aa, i, 0)) * aa[0*4 + c];
      #pragma unroll
      for (int k = 1; k < 8; ++k)
        s = FMA2(sp(EL(aa, i, k)), aa[k*4 + c], s);
      a2[i*4 + c] = s;
    }

  // A4 = A2*A2
  f2 a4[32];
  #pragma unroll
  for (int i = 0; i < 8; ++i)
    #pragma unroll
    for (int c = 0; c < 4; ++c) {
      f2 s = sp(EL(a2, i, 0)) * a2[0*4 + c];
      #pragma unroll
      for (int k = 1; k < 8; ++k)
        s = FMA2(sp(EL(a2, i, k)), a2[k*4 + c], s);
      a4[i*4 + c] = s;
    }

  // A6 = A4*A2
  f2 w6[32];
  #pragma unroll
  for (int i = 0; i < 8; ++i)
    #pragma unroll
    for (int c = 0; c < 4; ++c) {
      f2 s = sp(EL(a4, i, 0)) * a2[0*4 + c];
      #pragma unroll
      for (int k = 1; k < 8; ++k)
        s = FMA2(sp(EL(a4, i, k)), a2[k*4 + c], s);
      w6[i*4 + c] = s;
    }

  // XLA backend-fused polynomial combine (validated R3), j-paired:
  //   W = fma(277200, A2, fma(1512, A4, A6)) + diag(8648640)   (into w6)
  //   V = fma(1995840, A2, fma(56, A6, 25200*A4)) + diag(17297280)
  f2 vv[32];
  #pragma unroll
  for (int e = 0; e < 32; ++e) {
    f2 x6 = w6[e], x4 = a4[e], x2 = a2[e];
    f2 w = FMA2(sp(1512.0f), x4, x6);
    w = FMA2(sp(277200.0f), x2, w);
    f2 v = FMA2(sp(56.0f), x6, sp(25200.0f) * x4);
    v = FMA2(sp(1995840.0f), x2, v);
    w6[e] = w; vv[e] = v;
  }
  #pragma unroll
  for (int i = 0; i < 8; ++i) {   // diagonal adds (scalar halves)
    EL(w6, i, i) = EL(w6, i, i) + 8648640.0f;
    EL(vv, i, i) = EL(vv, i, i) + 17297280.0f;
  }

  // U = A @ W  (full chains; k==i term is fmaf(+-0,y,s)==s — R5-equivalent)
  f2 uu[32];
  #pragma unroll
  for (int i = 0; i < 8; ++i)
    #pragma unroll
    for (int c = 0; c < 4; ++c) {
      f2 s = sp(EL(aa, i, 0)) * w6[0*4 + c];
      #pragma unroll
      for (int k = 1; k < 8; ++k)
        s = FMA2(sp(EL(aa, i, k)), w6[k*4 + c], s);
      uu[i*4 + c] = s;
    }

  // P = U + V (into uu), Q = V - U (into vv) — pk add/sub, per-lane exact
  #pragma unroll
  for (int e = 0; e < 32; ++e) {
    f2 U = uu[e], V = vv[e];
    uu[e] = U + V;
    vv[e] = V - U;
  }
  f2* P = uu;
  f2* Q = vv;

  // ---- fused augmented elimination on [Q|P]: getrf(Q) + laswp(P) +
  // unit-lower trsm, interleaved per step k (bit-identical — header).
  // POST-PEAK CUTS: in-place f2 swap over live Q pairs; pk Q trailing update.
  #pragma unroll
  for (int k = 0; k < 8; ++k) {
    float amax = fabsf(EL(Q, k, k)); int jp = k;
    #pragma unroll
    for (int i = k+1; i < 8; ++i) {
      float av = fabsf(EL(Q, i, k));
      if (av > amax) { amax = av; jp = i; }   // first max, like isamax
    }
    const int c0 = k >> 1;
    // swap rows k<->jp: in-place progressive (d true at most once), Q live
    // pairs only + all P pairs
    #pragma unroll
    for (int i = k+1; i < 8; ++i) {
      bool d = (jp == i);
      #pragma unroll
      for (int c = c0; c < 4; ++c) {
        f2 qk = Q[k*4 + c], qi = Q[i*4 + c];
        Q[k*4 + c] = sel2(d, qi, qk);
        Q[i*4 + c] = sel2(d, qk, qi);
      }
      #pragma unroll
      for (int c = 0; c < 4; ++c) {
        f2 pk_ = P[k*4 + c], pi = P[i*4 + c];
        P[k*4 + c] = sel2(d, pi, pk_);
        P[i*4 + c] = sel2(d, pk_, pi);
      }
    }
    // pivot-column scale: direct IEEE divide (validated R3)
    float dk = EL(Q, k, k);
    #pragma unroll
    for (int i = k+1; i < 8; ++i) EL(Q, i, k) = EL(Q, i, k) / dk;
    // trailing updates: Q pk pairs over live columns (lik read first; dead
    // lanes j<=k get unread garbage) + P row-axpy (pk, independent elems)
    #pragma unroll
    for (int i = k+1; i < 8; ++i) {
      float lik = EL(Q, i, k);
      f2 nl = sp(-lik);
      #pragma unroll
      for (int c = c0; c < 4; ++c)
        Q[i*4 + c] = FMA2(nl, Q[k*4 + c], Q[i*4 + c]);
      #pragma unroll
      for (int c = 0; c < 4; ++c)
        P[i*4 + c] = FMA2(nl, P[k*4 + c], P[i*4 + c]);
    }
  }

  // strsm: non-unit upper, k descending, IEEE f32 divide per element
  #pragma unroll
  for (int k = 7; k >= 0; --k) {
    float dk = EL(Q, k, k);
    #pragma unroll
    for (int j = 0; j < 8; ++j) EL(P, k, j) = EL(P, k, j) / dk;
    #pragma unroll
    for (int i = 0; i < k; ++i) {
      f2 nu = sp(-EL(Q, i, k));
      #pragma unroll
      for (int c = 0; c < 4; ++c)
        P[i*4 + c] = FMA2(nu, P[k*4 + c], P[i*4 + c]);
    }
  }

  // repeated squaring (ns in {0,1} statistically)
  for (int sq = 0; sq < ns; ++sq) {
    f2 t2[32];
    mm8p(P, P, t2);
    #pragma unroll
    for (int e = 0; e < 32; ++e) P[e] = t2[e];
  }

  // gram = R^T R - I: bitwise symmetric -> compute pairs with 2c+1 >= i,
  // weight off-diag x2 (exact doubling), diag x1, duplicate-lower-lane x0.
  // Per-element chains identical; only the f32 sum order differs (invisible;
  // HW-validated R9/R10/R11).
  f2 s2p = sp(0.0f);
  #pragma unroll
  for (int i = 0; i < 8; ++i) {
    #pragma unroll
    for (int c = 0; c < 4; ++c) {
      if (2*c + 1 >= i) {
        f2 g = sp(EL(P, 0, i)) * P[0*4 + c];
        #pragma unroll
        for (int j = 1; j < 8; ++j)
          g = FMA2(sp(EL(P, j, i)), P[j*4 + c], g);
        f2 idv; idv.x = (2*c == i) ? 1.0f : 0.0f;
        idv.y = (2*c + 1 == i) ? 1.0f : 0.0f;
        f2 e = g - idv;
        f2 we;
        we.x = (2*c > i) ? (e.x + e.x) : ((2*c == i) ? e.x : 0.0f);
        we.y = (2*c + 1 == i) ? e.y : (e.y + e.y);
        s2p = FMA2(we, e, s2p);
      }
    }
  }
  float frob = sqrtf(s2p.x + s2p.y);

  // wave shuffle reduce (f64) -> LDS -> one atomic per 256-thread block
  double dv = (double)frob;
  #pragma unroll
  for (int off = 32; off > 0; off >>= 1)
    dv += __shfl_down(dv, off);

  __shared__ double part[4];
  const int lane = threadIdx.x & 63;
  const int wid  = threadIdx.x >> 6;
  if (lane == 0) part[wid] = dv;
  __syncthreads();
  if (threadIdx.x == 0) {
    double s = (part[0] + part[1]) + (part[2] + part[3]);
    atomicAdd(acc, s);
  }
}

__global__ void finalize_kernel(const double* __restrict__ acc,
                                float* __restrict__ out, int nmat)
{
  out[0] = (float)(acc[0] / (double)nmat);
}

extern "C" void kernel_launch(void* const* d_in, const int* in_sizes, int n_in,
                              void* d_out, int out_size, void* d_ws, size_t ws_size,
                              hipStream_t stream) {
  const float* in = (const float*)d_in[0];
  float* out = (float*)d_out;
  double* acc = (double*)d_ws;
  int nmat = in_sizes[0] / 64;   // 524288
  hipMemsetAsync(d_ws, 0, sizeof(double), stream);
  triality_kernel<<<nmat / 256, 256, 0, stream>>>(in, acc);
  finalize_kernel<<<1, 1, 0, stream>>>(acc, out, nmat);
}